// Round 18
// baseline (112.212 us; speedup 1.0000x reference)
//
#include <hip/hip_runtime.h>
#include <stdint.h>

// Problem constants
#define B_SZ 8
#define T_SZ 1024
#define DM   768
#define NH   12
#define DH   64
#define NTOK (B_SZ * T_SZ)   // 8192
#define NOUT (NTOK * DM)     // 6291456
#define INF  __builtin_inff()

typedef unsigned short u16;
typedef __attribute__((ext_vector_type(8))) short short8;   // 8 bf16 (4 VGPRs) MFMA frag
typedef __attribute__((ext_vector_type(4))) short short4v;
typedef __attribute__((ext_vector_type(4))) float f32x4;

#define MFMA16x16x32 __builtin_amdgcn_mfma_f32_16x16x32_bf16

__device__ __forceinline__ u16 f2bf(float f) {
    unsigned u = __builtin_bit_cast(unsigned, f);
    u += 0x7fffu + ((u >> 16) & 1u);   // RNE
    return (u16)(u >> 16);
}

__device__ __forceinline__ f32x4 max4(f32x4 a, f32x4 b) {
    f32x4 r; r.x = fmaxf(a.x, b.x); r.y = fmaxf(a.y, b.y);
    r.z = fmaxf(a.z, b.z); r.w = fmaxf(a.w, b.w); return r;
}
__device__ __forceinline__ f32x4 add4(f32x4 a, f32x4 b) {
    f32x4 r; r.x = a.x + b.x; r.y = a.y + b.y;
    r.z = a.z + b.z; r.w = a.w + b.w; return r;
}

// CK-proven pattern: integer-cast to AS1/AS3 pointers for the direct-to-LDS load.
__device__ __forceinline__ void gload16(const void* g, void* l) {
    __builtin_amdgcn_global_load_lds(
        (const __attribute__((address_space(1))) unsigned int*)(unsigned long long)(uintptr_t)g,
        (__attribute__((address_space(3))) unsigned int*)(unsigned int)(uintptr_t)l,
        16, 0, 0);
}

// ---------------- fused prep: X->bf16, Wa^T->bf16, Wp^T->bf16 ----------------
__global__ __launch_bounds__(256) void prep_kernel(
    const float* __restrict__ hs, u16* __restrict__ Xbf,
    const float* __restrict__ Wa, u16* __restrict__ WaT,
    const float* __restrict__ Wp, u16* __restrict__ WpT)
{
    __shared__ float tile[32][33];
    const int bid = blockIdx.x;
    if (bid < 6144) {
        const int i = bid * 1024 + threadIdx.x * 4;
        f32x4 v = *(const f32x4*)(hs + i);
        short4v o;
        o.x = (short)f2bf(v.x); o.y = (short)f2bf(v.y);
        o.z = (short)f2bf(v.z); o.w = (short)f2bf(v.w);
        *(short4v*)(Xbf + i) = o;
        return;
    }
    const float* in; u16* out; int R, C, bx, by;
    if (bid < 6144 + 1728) {
        const int lid = bid - 6144;
        in = Wa; out = WaT; R = 768; C = 2304; bx = lid % 72; by = lid / 72;
    } else {
        const int lid = bid - 7872;
        in = Wp; out = WpT; R = 768; C = 768; bx = lid % 24; by = lid / 24;
    }
    const int tx = threadIdx.x & 31, ty = threadIdx.x >> 5;
    const int c0 = bx * 32, r0 = by * 32;
    for (int i = ty; i < 32; i += 8)
        tile[i][tx] = in[(size_t)(r0 + i) * C + c0 + tx];
    __syncthreads();
    for (int i = ty; i < 32; i += 8)
        out[(size_t)(c0 + i) * R + r0 + tx] = f2bf(tile[tx][i]);
}

// ---------------- bf16 QKV GEMM, 128x96 tile, 3-buf / 1-barrier pipeline ----------------
// Round-18: BN 128->96 -> grid 64x24 = 1536 blocks = exactly 2 per slot at
// 3 blocks/CU (r17 QKV was 1152/768 slots = 75% utilization). Same proven
// pipeline; waves 2x2 of 64x48 (acc[4][3]). B rows 64-95 staged by waves 0-1
// only (wave-uniform vmcnt; WAITBAR(3) safe for 4- and 3-load waves — proj-proven).
// Epilogue: per-16-col h/dd in phase A; per-8-col-chunk addressing in phase B.
__global__ __launch_bounds__(256, 3) void gemm_qkv_kernel(
    const u16* __restrict__ A, const u16* __restrict__ BT, const float* __restrict__ bias,
    u16* __restrict__ qbf, u16* __restrict__ kbf, u16* __restrict__ vtb,
    float* __restrict__ outK, float* __restrict__ outV)
{
    __shared__ alignas(16) u16 SMEM[21504];       // 42 KB: 3 x (A 4096 + B 3072) u16
#define ASP(b) (SMEM + (b) * 4096)
#define BSP(b) (SMEM + 12288 + (b) * 3072)
    const int t   = threadIdx.x;
    const int wid = t >> 6, l = t & 63;
    const int lr  = l & 15, g = l >> 4;
    const int m0  = blockIdx.x * 128, n0 = blockIdx.y * 96;
    const int wm  = (wid >> 1) * 64, wn = (wid & 1) * 48;

    const int srow = t >> 2;
    const int sch  = ((t & 3) ^ ((srow >> 1) & 3)) * 8;
    const u16* ga0 = A  + (size_t)(m0 + srow) * 768 + sch;
    const u16* ga1 = A  + (size_t)(m0 + 64 + srow) * 768 + sch;
    const u16* gb0 = BT + (size_t)(n0 + srow) * 768 + sch;
    const u16* gb1 = BT + (size_t)(n0 + 64 + srow) * 768 + sch;  // rows 64-95, t<128
    const bool doB1 = (t < 128);

#define GSTAGE(buf, kt) do {                                        \
        gload16(ga0 + (kt) * 32, ASP(buf) + t * 8);                 \
        gload16(ga1 + (kt) * 32, ASP(buf) + 2048 + t * 8);          \
        gload16(gb0 + (kt) * 32, BSP(buf) + t * 8);                 \
        if (doB1) gload16(gb1 + (kt) * 32, BSP(buf) + 2048 + t * 8);\
    } while (0)

    const int fco = (g ^ ((lr >> 1) & 3)) * 8;

    f32x4 acc[4][3] = {};

#define COMPUTE(buf) do {                                                 \
        const u16* aB = ASP(buf);                                         \
        const u16* bB = BSP(buf);                                         \
        short8 af[4], bfr[3];                                             \
        _Pragma("unroll")                                                 \
        for (int i = 0; i < 4; ++i)                                       \
            af[i] = *(const short8*)(aB + (wm + i * 16 + lr) * 32 + fco); \
        _Pragma("unroll")                                                 \
        for (int j = 0; j < 3; ++j)                                       \
            bfr[j] = *(const short8*)(bB + (wn + j * 16 + lr) * 32 + fco);\
        __builtin_amdgcn_s_setprio(1);                                    \
        _Pragma("unroll")                                                 \
        for (int i = 0; i < 4; ++i)                                       \
            _Pragma("unroll")                                             \
            for (int j = 0; j < 3; ++j)                                   \
                acc[i][j] = MFMA16x16x32(af[i], bfr[j], acc[i][j], 0, 0, 0);\
        __builtin_amdgcn_s_setprio(0);                                    \
    } while (0)

#define WAITBAR(N) do {                                           \
        asm volatile("s_waitcnt vmcnt(" #N ")" ::: "memory");     \
        __builtin_amdgcn_s_barrier();                             \
        __builtin_amdgcn_sched_barrier(0);                        \
    } while (0)

    GSTAGE(0, 0); GSTAGE(1, 1);
    WAITBAR(3);

    #pragma unroll 1
    for (int i = 0; i < 7; ++i) {
        const int kt = i * 3;
        GSTAGE(2, kt + 2); COMPUTE(0); WAITBAR(3);
        GSTAGE(0, kt + 3); COMPUTE(1); WAITBAR(3);
        GSTAGE(1, kt + 4); COMPUTE(2); WAITBAR(3);
    }
    GSTAGE(2, 23); COMPUTE(0); WAITBAR(3);
    COMPUTE(1); WAITBAR(0);
    COMPUTE(2);
#undef GSTAGE
#undef COMPUTE
#undef WAITBAR

    // ---------------- epilogue (LDS-reorder; per-chunk head addressing) ----------------
    // C/D layout: col = lane&15, row = (lane>>4)*4 + reg. Wave tile 64 tau x 48 dd.
    __builtin_amdgcn_s_barrier();                // all waves done with staging LDS
    const int nbase = n0 + wn;                   // 48-aligned
    const int which = nbase / 768;               // uniform (96 | 768)
    const int lbase = nbase - which * 768;
    const int b = (m0 + wm) >> 10, tt0 = (m0 + wm) & 1023;
    const size_t bh12 = (size_t)(b * 12);

    if (which == 0) {
        u16* EL = SMEM + wid * 3584;             // 64 rows x 56 u16
        #pragma unroll
        for (int j = 0; j < 3; ++j) {
            const float bn = bias[nbase + j * 16 + lr];
            #pragma unroll
            for (int i = 0; i < 4; ++i)
                #pragma unroll
                for (int r = 0; r < 4; ++r) {
                    const int tau = i * 16 + g * 4 + r;
                    EL[tau * 56 + j * 16 + lr] =
                        f2bf((acc[i][j][r] + bn) * (0.125f * 1.44269504f));
                }
        }
        asm volatile("s_waitcnt lgkmcnt(0)" ::: "memory");
        __builtin_amdgcn_sched_barrier(0);
        #pragma unroll
        for (int it = 0; it < 6; ++it) {
            const int idx = it * 64 + l;         // 0..383
            const int tau = idx / 6, ch = idx - 6 * tau;
            const int lc = lbase + ch * 8;
            const int h = lc >> 6, dd = lc & 63;
            *(short8*)(qbf + ((bh12 + h) * 1024 + tt0 + tau) * 64 + dd) =
                *(const short8*)(EL + tau * 56 + ch * 8);
        }
    } else if (which == 1) {
        u16* EL = SMEM + wid * 3584;
        #pragma unroll
        for (int j = 0; j < 3; ++j) {
            const int lc = lbase + j * 16;
            const int h = lc >> 6, ddb = (lc & 63) + lr;
            const float bn = bias[nbase + j * 16 + lr];
            #pragma unroll
            for (int i = 0; i < 4; ++i)
                #pragma unroll
                for (int r = 0; r < 4; ++r) {
                    const int tau = i * 16 + g * 4 + r;
                    const float v = acc[i][j][r] + bn;
                    EL[tau * 56 + j * 16 + lr] = f2bf(v);
                    outK[((bh12 + h) * 1024 + tt0 + tau) * 64 + ddb] = v;
                }
        }
        asm volatile("s_waitcnt lgkmcnt(0)" ::: "memory");
        __builtin_amdgcn_sched_barrier(0);
        #pragma unroll
        for (int it = 0; it < 6; ++it) {
            const int idx = it * 64 + l;
            const int tau = idx / 6, ch = idx - 6 * tau;
            const int lc = lbase + ch * 8;
            const int h = lc >> 6, dd = lc & 63;
            *(short8*)(kbf + ((bh12 + h) * 1024 + tt0 + tau) * 64 + dd) =
                *(const short8*)(EL + tau * 56 + ch * 8);
        }
    } else {
        u16* EL = SMEM + wid * 3456;             // 48 rows (dd) x 72 u16 (tau cols)
        #pragma unroll
        for (int j = 0; j < 3; ++j) {
            const int lc = lbase + j * 16;
            const int h = lc >> 6, ddb = (lc & 63) + lr;
            const float bn = bias[nbase + j * 16 + lr];
            #pragma unroll
            for (int i = 0; i < 4; ++i)
                #pragma unroll
                for (int r = 0; r < 4; ++r) {
                    const int tau = i * 16 + g * 4 + r;
                    const float v = acc[i][j][r] + bn;
                    outV[((bh12 + h) * 1024 + tt0 + tau) * 64 + ddb] = v;
                    EL[(j * 16 + lr) * 72 + tau] = f2bf(v);   // [dd_local][tau]
                }
        }
        asm volatile("s_waitcnt lgkmcnt(0)" ::: "memory");
        __builtin_amdgcn_sched_barrier(0);
        #pragma unroll
        for (int it = 0; it < 6; ++it) {
            const int idx = it * 64 + l;         // 0..383
            const int row = idx >> 3, c = idx & 7;   // dd_local, tau-chunk
            const int lc = lbase + row;
            const int h = lc >> 6, dd = lc & 63;
            *(short8*)(vtb + (bh12 + h) * 65536 + (size_t)dd * 1024 + tt0 + c * 8) =
                *(const short8*)(EL + row * 72 + c * 8);
        }
    }
#undef ASP
#undef BSP
}

// ---------------- proj GEMM: 128x96 tile -> 512 blocks = exactly 2/CU, balanced ----------------
__global__ __launch_bounds__(256, 3) void gemm_proj_kernel(
    const u16* __restrict__ A, const u16* __restrict__ BT,
    const float* __restrict__ bias, float* __restrict__ outP)
{
    __shared__ alignas(16) u16 As[3][128 * 32];   // 8 KB each
    __shared__ alignas(16) u16 Bs[3][96 * 32];    // 6 KB each  (42 KB total)
    const int t   = threadIdx.x;
    const int wid = t >> 6, l = t & 63;
    const int lr  = l & 15, g = l >> 4;
    const int m0  = blockIdx.x * 128, n0 = blockIdx.y * 96;
    const int wm  = (wid >> 1) * 64, wn = (wid & 1) * 48;

    const int srow = t >> 2;
    const int sch  = ((t & 3) ^ ((srow >> 1) & 3)) * 8;
    const u16* ga0 = A  + (size_t)(m0 + srow) * 768 + sch;
    const u16* ga1 = A  + (size_t)(m0 + 64 + srow) * 768 + sch;
    const u16* gb0 = BT + (size_t)(n0 + srow) * 768 + sch;
    const u16* gb1 = BT + (size_t)(n0 + 64 + srow) * 768 + sch;  // rows 64-95, t<128
    const bool doB1 = (t < 128);

#define GSTAGE(buf, kt) do {                                        \
        gload16(ga0 + (kt) * 32, As[buf] + t * 8);                  \
        gload16(ga1 + (kt) * 32, As[buf] + 2048 + t * 8);           \
        gload16(gb0 + (kt) * 32, Bs[buf] + t * 8);                  \
        if (doB1) gload16(gb1 + (kt) * 32, Bs[buf] + 2048 + t * 8); \
    } while (0)

    const int fco = (g ^ ((lr >> 1) & 3)) * 8;

    f32x4 acc[4][3] = {};

#define COMPUTE(buf) do {                                                 \
        const u16* aB = As[buf];                                          \
        const u16* bB = Bs[buf];                                          \
        short8 af[4], bfr[3];                                             \
        _Pragma("unroll")                                                 \
        for (int i = 0; i < 4; ++i)                                       \
            af[i] = *(const short8*)(aB + (wm + i * 16 + lr) * 32 + fco); \
        _Pragma("unroll")                                                 \
        for (int j = 0; j < 3; ++j)                                       \
            bfr[j] = *(const short8*)(bB + (wn + j * 16 + lr) * 32 + fco);\
        __builtin_amdgcn_s_setprio(1);                                    \
        _Pragma("unroll")                                                 \
        for (int i = 0; i < 4; ++i)                                       \
            _Pragma("unroll")                                             \
            for (int j = 0; j < 3; ++j)                                   \
                acc[i][j] = MFMA16x16x32(af[i], bfr[j], acc[i][j], 0, 0, 0);\
        __builtin_amdgcn_s_setprio(0);                                    \
    } while (0)

#define WAITBAR(N) do {                                           \
        asm volatile("s_waitcnt vmcnt(" #N ")" ::: "memory");     \
        __builtin_amdgcn_s_barrier();                             \
        __builtin_amdgcn_sched_barrier(0);                        \
    } while (0)

    GSTAGE(0, 0); GSTAGE(1, 1);
    WAITBAR(3);

    #pragma unroll 1
    for (int i = 0; i < 7; ++i) {
        const int kt = i * 3;
        GSTAGE(2, kt + 2); COMPUTE(0); WAITBAR(3);
        GSTAGE(0, kt + 3); COMPUTE(1); WAITBAR(3);
        GSTAGE(1, kt + 4); COMPUTE(2); WAITBAR(3);
    }
    GSTAGE(2, 23); COMPUTE(0); WAITBAR(3);
    COMPUTE(1); WAITBAR(0);
    COMPUTE(2);
#undef GSTAGE
#undef COMPUTE
#undef WAITBAR

    #pragma unroll
    for (int j = 0; j < 3; ++j) {
        const int n = n0 + wn + j * 16 + lr;
        const float bn = bias[n];
        #pragma unroll
        for (int i = 0; i < 4; ++i)
            #pragma unroll
            for (int r = 0; r < 4; ++r) {
                const int m = m0 + wm + i * 16 + g * 4 + r;
                outP[(size_t)m * 768 + n] = acc[i][j][r] + bn;
            }
    }
}

// ---------------- causal flash attention, LDS-staged K AND V (round-13 proven) ----------------
__global__ __launch_bounds__(256, 3) void attn_kernel(
    const u16* __restrict__ Qb, const u16* __restrict__ Kb,
    const u16* __restrict__ Vt, u16* __restrict__ Ob)
{
    __shared__ alignas(16) u16 Ks[2][4096];     // [64 kt][8 chunks of 8 u16], swizzled
    __shared__ alignas(16) u16 Vs[2][4096];     // [64 d ][8 chunks of 8 u16], swizzled
    __shared__ alignas(16) u16 Pl[4][16 * 72];  // per-wave P: 16 q x (64+8 pad) u16
    const int bh = blockIdx.x;
    const int t = threadIdx.x;
    const int wid = t >> 6, l = t & 63;
    const int c = l & 15, g = l >> 4;
    u16* P = Pl[wid];
    const u16* Kp = Kb + (size_t)bh * 65536;    // [T][64]
    const u16* Vp = Vt + (size_t)bh * 65536;    // [64][T]
    const int b = bh / 12, h = bh - (bh / 12) * 12;

    const int srow = t >> 3;
    const int sch  = (t & 7) ^ (srow & 7);
    const u16* Ksrc0 = Kp + (size_t)srow * 64 + sch * 8;
    const u16* Ksrc1 = Kp + (size_t)(srow + 32) * 64 + sch * 8;
    const u16* Vsrc0 = Vp + (size_t)srow * 1024 + sch * 8;
    const u16* Vsrc1 = Vp + (size_t)(srow + 32) * 1024 + sch * 8;

    const int fo0 = c * 64 + ((g ^ (c & 7)) * 8);
    const int fo1 = c * 64 + (((g + 4) ^ (c & 7)) * 8);

#define STAGE(buf, kt0) do {                                        \
        gload16(Ksrc0 + (size_t)(kt0) * 64, Ks[buf] + t * 8);       \
        gload16(Ksrc1 + (size_t)(kt0) * 64, Ks[buf] + 2048 + t * 8);\
        gload16(Vsrc0 + (kt0),              Vs[buf] + t * 8);       \
        gload16(Vsrc1 + (kt0),              Vs[buf] + 2048 + t * 8);\
    } while (0)

    #pragma unroll 1
    for (int pass = 0; pass < 2; ++pass) {
        const int tile = pass ? (15 - blockIdx.y) : blockIdx.y;
        const int qbase = tile * 64 + wid * 16;
        const int qg = qbase + c;                // this lane's q column
        const u16* Qp = Qb + ((size_t)bh * 1024 + qg) * 64 + g * 8;
        const short8 bq0 = *(const short8*)(Qp);
        const short8 bq1 = *(const short8*)(Qp + 32);

        f32x4 oacc[4] = {};
        float mrow = -INF, lpart = 0.f;
        const int nb = tile + 1;                 // 64-wide KV blocks

        STAGE(0, 0);
        __syncthreads();
        int cur = 0;

        #pragma unroll 1
        for (int kb = 0; kb < nb; ++kb) {
            if (kb + 1 < nb) STAGE(cur ^ 1, (kb + 1) << 6);
            const u16* kB = Ks[cur];
            const u16* vB = Vs[cur];
            short8 af0[4], af1[4], vf0[4], vf1[4];
            #pragma unroll
            for (int j = 0; j < 4; ++j) {
                af0[j] = *(const short8*)(kB + j * 1024 + fo0);
                af1[j] = *(const short8*)(kB + j * 1024 + fo1);
            }
            #pragma unroll
            for (int dt = 0; dt < 4; ++dt) {
                vf0[dt] = *(const short8*)(vB + dt * 1024 + fo0);
                vf1[dt] = *(const short8*)(vB + dt * 1024 + fo1);
            }
            // QK^T: D[kt][q], s[j] covers kt rows j*16 + g*4 + r
            f32x4 s[4] = {};
            __builtin_amdgcn_s_setprio(1);
            #pragma unroll
            for (int j = 0; j < 4; ++j) {
                s[j] = MFMA16x16x32(af0[j], bq0, s[j], 0, 0, 0);
                s[j] = MFMA16x16x32(af1[j], bq1, s[j], 0, 0, 0);
            }
            __builtin_amdgcn_s_setprio(0);
            if (kb == nb - 1) {                  // only diagonal block masks
                const int kt0 = kb << 6;
                #pragma unroll
                for (int j = 0; j < 4; ++j)
                    #pragma unroll
                    for (int r = 0; r < 4; ++r)
                        if (kt0 + j * 16 + g * 4 + r > qg) s[j][r] = -INF;
            }
            // softmax (scores already in log2 units); tree max
            f32x4 mm = max4(max4(s[0], s[1]), max4(s[2], s[3]));
            float tm = fmaxf(fmaxf(mm.x, mm.y), fmaxf(mm.z, mm.w));
            tm = fmaxf(tm, __shfl_xor(tm, 16));
            tm = fmaxf(tm, __shfl_xor(tm, 32));
            // defer-max (T13): skip rescale while growth <= 8 (log2 units)
            const bool keep = (__all(tm <= mrow + 8.f) != 0);
            const float mnew = keep ? mrow : fmaxf(mrow, tm);
            if (!keep) {
                const float sc = exp2f(mrow - mnew);
                mrow = mnew;
                lpart *= sc;
                #pragma unroll
                for (int dt = 0; dt < 4; ++dt) {
                    oacc[dt][0] *= sc; oacc[dt][1] *= sc;
                    oacc[dt][2] *= sc; oacc[dt][3] *= sc;
                }
            }
            f32x4 p[4];
            #pragma unroll
            for (int j = 0; j < 4; ++j) {
                p[j].x = exp2f(s[j].x - mnew); p[j].y = exp2f(s[j].y - mnew);
                p[j].z = exp2f(s[j].z - mnew); p[j].w = exp2f(s[j].w - mnew);
            }
            f32x4 ps = add4(add4(p[0], p[1]), add4(p[2], p[3]));
            lpart += (ps.x + ps.y) + (ps.z + ps.w);
            // P[q=c][kt] bf16 -> LDS (row stride 72 u16, 2-way conflicts only)
            #pragma unroll
            for (int j = 0; j < 4; ++j) {
                short4v w;
                w.x = (short)f2bf(p[j].x); w.y = (short)f2bf(p[j].y);
                w.z = (short)f2bf(p[j].z); w.w = (short)f2bf(p[j].w);
                *(short4v*)(P + c * 72 + j * 16 + g * 4) = w;
            }
            const short8 pf0 = *(const short8*)(P + c * 72 + g * 8);
            const short8 pf1 = *(const short8*)(P + c * 72 + 32 + g * 8);
            // PV: A = V^T rows (d), B = P^T -> D[d][q]
            __builtin_amdgcn_s_setprio(1);
            #pragma unroll
            for (int dt = 0; dt < 4; ++dt) {
                oacc[dt] = MFMA16x16x32(vf0[dt], pf0, oacc[dt], 0, 0, 0);
                oacc[dt] = MFMA16x16x32(vf1[dt], pf1, oacc[dt], 0, 0, 0);
            }
            __builtin_amdgcn_s_setprio(0);
            __syncthreads();   // drains staging (vmcnt 0) + all waves done with buf cur
            cur ^= 1;
        }
        float lsum = lpart;
        lsum += __shfl_xor(lsum, 16);
        lsum += __shfl_xor(lsum, 32);
        const float li = 1.f / lsum;             // lane-local (col=q layout)
        // O-write via per-wave LDS reorder -> 2x16-B coalesced stores/lane
        #pragma unroll
        for (int dt = 0; dt < 4; ++dt) {
            short4v w;
            w.x = (short)f2bf(oacc[dt][0] * li);
            w.y = (short)f2bf(oacc[dt][1] * li);
            w.z = (short)f2bf(oacc[dt][2] * li);
            w.w = (short)f2bf(oacc[dt][3] * li);
            *(short4v*)(P + c * 72 + dt * 16 + g * 4) = w;
        }
        asm volatile("s_waitcnt lgkmcnt(0)" ::: "memory");
        __builtin_amdgcn_sched_barrier(0);
        #pragma unroll
        for (int it = 0; it < 2; ++it) {
            const int idx = it * 64 + l;
            const int q = idx >> 3, ch = idx & 7;
            *(short8*)(Ob + (size_t)(b * 1024 + qbase + q) * 768 + h * 64 + ch * 8) =
                *(const short8*)(P + q * 72 + ch * 8);
        }
    }
#undef STAGE
}

extern "C" void kernel_launch(void* const* d_in, const int* in_sizes, int n_in,
                              void* d_out, int out_size, void* d_ws, size_t ws_size,
                              hipStream_t stream) {
    const float* hs = (const float*)d_in[0];   // [8,1024,768]
    const float* Wa = (const float*)d_in[1];   // [768,2304]
    const float* ba = (const float*)d_in[2];   // [2304]
    const float* Wp = (const float*)d_in[3];   // [768,768]
    const float* bp = (const float*)d_in[4];   // [768]
    float* out = (float*)d_out;                // out | K | V  (each NOUT fp32)

    u16* ws  = (u16*)d_ws;
    u16* Xbf = ws;                             // [8192][768]
    u16* WaT = Xbf + NOUT;                     // [2304][768]
    u16* WpT = WaT + 768 * 2304;               // [768][768]
    u16* Qbf = WpT + 768 * 768;                // [B,H,T,64] (pre-scaled by 0.125*log2e)
    u16* Kbf = Qbf + NOUT;                     // [B,H,T,64]
    u16* VTb = Kbf + NOUT;                     // [B,H,64,T]
    u16* Obf = VTb + NOUT;                     // [8192][768]

    prep_kernel<<<8448, 256, 0, stream>>>(hs, Xbf, Wa, WaT, Wp, WpT);
    gemm_qkv_kernel<<<dim3(64, 24), 256, 0, stream>>>(
        Xbf, WaT, ba, Qbf, Kbf, VTb, out + NOUT, out + 2 * (size_t)NOUT);
    attn_kernel<<<dim3(96, 8), 256, 0, stream>>>(Qbf, Kbf, VTb, Obf);
    gemm_proj_kernel<<<dim3(64, 8), 256, 0, stream>>>(Obf, WpT, bp, out);
}

// Round 19
// 108.928 us; speedup vs baseline: 1.0302x; 1.0302x over previous
//
#include <hip/hip_runtime.h>
#include <stdint.h>

// Problem constants
#define B_SZ 8
#define T_SZ 1024
#define DM   768
#define NH   12
#define DH   64
#define NTOK (B_SZ * T_SZ)   // 8192
#define NOUT (NTOK * DM)     // 6291456
#define INF  __builtin_inff()

typedef unsigned short u16;
typedef __attribute__((ext_vector_type(8))) short short8;   // 8 bf16 (4 VGPRs) MFMA frag
typedef __attribute__((ext_vector_type(4))) short short4v;
typedef __attribute__((ext_vector_type(4))) float f32x4;

#define MFMA16x16x32 __builtin_amdgcn_mfma_f32_16x16x32_bf16

__device__ __forceinline__ u16 f2bf(float f) {
    unsigned u = __builtin_bit_cast(unsigned, f);
    u += 0x7fffu + ((u >> 16) & 1u);   // RNE
    return (u16)(u >> 16);
}

__device__ __forceinline__ f32x4 max4(f32x4 a, f32x4 b) {
    f32x4 r; r.x = fmaxf(a.x, b.x); r.y = fmaxf(a.y, b.y);
    r.z = fmaxf(a.z, b.z); r.w = fmaxf(a.w, b.w); return r;
}
__device__ __forceinline__ f32x4 add4(f32x4 a, f32x4 b) {
    f32x4 r; r.x = a.x + b.x; r.y = a.y + b.y;
    r.z = a.z + b.z; r.w = a.w + b.w; return r;
}

// CK-proven pattern: integer-cast to AS1/AS3 pointers for the direct-to-LDS load.
__device__ __forceinline__ void gload16(const void* g, void* l) {
    __builtin_amdgcn_global_load_lds(
        (const __attribute__((address_space(1))) unsigned int*)(unsigned long long)(uintptr_t)g,
        (__attribute__((address_space(3))) unsigned int*)(unsigned int)(uintptr_t)l,
        16, 0, 0);
}

// ---------------- fused prep: X->bf16, Wa^T->bf16, Wp^T->bf16 ----------------
__global__ __launch_bounds__(256) void prep_kernel(
    const float* __restrict__ hs, u16* __restrict__ Xbf,
    const float* __restrict__ Wa, u16* __restrict__ WaT,
    const float* __restrict__ Wp, u16* __restrict__ WpT)
{
    __shared__ float tile[32][33];
    const int bid = blockIdx.x;
    if (bid < 6144) {
        const int i = bid * 1024 + threadIdx.x * 4;
        f32x4 v = *(const f32x4*)(hs + i);
        short4v o;
        o.x = (short)f2bf(v.x); o.y = (short)f2bf(v.y);
        o.z = (short)f2bf(v.z); o.w = (short)f2bf(v.w);
        *(short4v*)(Xbf + i) = o;
        return;
    }
    const float* in; u16* out; int R, C, bx, by;
    if (bid < 6144 + 1728) {
        const int lid = bid - 6144;
        in = Wa; out = WaT; R = 768; C = 2304; bx = lid % 72; by = lid / 72;
    } else {
        const int lid = bid - 7872;
        in = Wp; out = WpT; R = 768; C = 768; bx = lid % 24; by = lid / 24;
    }
    const int tx = threadIdx.x & 31, ty = threadIdx.x >> 5;
    const int c0 = bx * 32, r0 = by * 32;
    for (int i = ty; i < 32; i += 8)
        tile[i][tx] = in[(size_t)(r0 + i) * C + c0 + tx];
    __syncthreads();
    for (int i = ty; i < 32; i += 8)
        out[(size_t)(c0 + i) * R + r0 + tx] = f2bf(tile[tx][i]);
}

// ---------------- bf16 QKV GEMM, 128x128 tile, 3-buf / 1-barrier pipeline ----------------
// Frozen round-13 state (48 KB LDS, 3 blocks/CU, counted vmcnt(4), LDS-reorder
// epilogue incl. transposed V^T dump). Measured 47 us / MfmaUtil 23.6.
// Round-18 lesson: the K-loop iteration time is a latency floor — shrinking the
// tile (128x96) removed hidden MFMA work but added block overhead (-9% perf).
// 128x128 at 1152 blocks is the local optimum of this structure.
template <int EPI>
__global__ __launch_bounds__(256, 3) void gemm_k768_kernel(
    const u16* __restrict__ A, const u16* __restrict__ BT, const float* __restrict__ bias,
    u16* __restrict__ qbf, u16* __restrict__ kbf, u16* __restrict__ vtb,
    float* __restrict__ outK, float* __restrict__ outV, float* __restrict__ outP)
{
    __shared__ alignas(16) u16 SMEM[24576];       // 48 KB: 3x(A 8KB + B 8KB) / epi scratch
#define ASP(b) (SMEM + (b) * 4096)
#define BSP(b) (SMEM + 12288 + (b) * 4096)
    const int t   = threadIdx.x;
    const int wid = t >> 6, l = t & 63;
    const int lr  = l & 15, g = l >> 4;
    const int m0  = blockIdx.x * 128, n0 = blockIdx.y * 128;
    const int wm  = (wid >> 1) * 64, wn = (wid & 1) * 64;

    const int srow = t >> 2;
    const int sch  = ((t & 3) ^ ((srow >> 1) & 3)) * 8;
    const u16* ga0 = A  + (size_t)(m0 + srow) * 768 + sch;
    const u16* ga1 = A  + (size_t)(m0 + 64 + srow) * 768 + sch;
    const u16* gb0 = BT + (size_t)(n0 + srow) * 768 + sch;
    const u16* gb1 = BT + (size_t)(n0 + 64 + srow) * 768 + sch;

#define GSTAGE(buf, kt) do {                              \
        gload16(ga0 + (kt) * 32, ASP(buf) + t * 8);       \
        gload16(ga1 + (kt) * 32, ASP(buf) + 2048 + t * 8);\
        gload16(gb0 + (kt) * 32, BSP(buf) + t * 8);       \
        gload16(gb1 + (kt) * 32, BSP(buf) + 2048 + t * 8);\
    } while (0)

    const int fco = (g ^ ((lr >> 1) & 3)) * 8;

    f32x4 acc[4][4] = {};

#define COMPUTE(buf) do {                                                 \
        const u16* aB = ASP(buf);                                         \
        const u16* bB = BSP(buf);                                         \
        short8 af[4], bfr[4];                                             \
        _Pragma("unroll")                                                 \
        for (int i = 0; i < 4; ++i)                                       \
            af[i] = *(const short8*)(aB + (wm + i * 16 + lr) * 32 + fco); \
        _Pragma("unroll")                                                 \
        for (int j = 0; j < 4; ++j)                                       \
            bfr[j] = *(const short8*)(bB + (wn + j * 16 + lr) * 32 + fco);\
        __builtin_amdgcn_s_setprio(1);                                    \
        _Pragma("unroll")                                                 \
        for (int i = 0; i < 4; ++i)                                       \
            _Pragma("unroll")                                             \
            for (int j = 0; j < 4; ++j)                                   \
                acc[i][j] = MFMA16x16x32(af[i], bfr[j], acc[i][j], 0, 0, 0);\
        __builtin_amdgcn_s_setprio(0);                                    \
    } while (0)

#define WAITBAR(N) do {                                           \
        asm volatile("s_waitcnt vmcnt(" #N ")" ::: "memory");     \
        __builtin_amdgcn_s_barrier();                             \
        __builtin_amdgcn_sched_barrier(0);                        \
    } while (0)

    GSTAGE(0, 0); GSTAGE(1, 1);
    WAITBAR(4);

    #pragma unroll 1
    for (int i = 0; i < 7; ++i) {
        const int kt = i * 3;
        GSTAGE(2, kt + 2); COMPUTE(0); WAITBAR(4);
        GSTAGE(0, kt + 3); COMPUTE(1); WAITBAR(4);
        GSTAGE(1, kt + 4); COMPUTE(2); WAITBAR(4);
    }
    GSTAGE(2, 23); COMPUTE(0); WAITBAR(4);
    COMPUTE(1); WAITBAR(0);
    COMPUTE(2);
#undef GSTAGE
#undef COMPUTE
#undef WAITBAR

    // ---------------- epilogue (LDS-reorder, round-12/13 verified) ----------------
    if (EPI == 0) {
        __builtin_amdgcn_s_barrier();            // all waves done with staging LDS
        u16* EL = SMEM + wid * 4608;             // 64 rows x 72 u16 per wave
        const int nbase = n0 + wn;
        const int which = nbase / 768;           // 0=Q,1=K,2=V
        const int h = ((nbase - which * 768) >> 6);
        const int b = (m0 + wm) >> 10, tt0 = (m0 + wm) & 1023;
        const size_t rowbase = (size_t)(b * 12 + h) * 1024 + tt0;
        if (which == 0) {
            #pragma unroll
            for (int j = 0; j < 4; ++j) {
                const float bn = bias[nbase + j * 16 + lr];
                #pragma unroll
                for (int i = 0; i < 4; ++i)
                    #pragma unroll
                    for (int r = 0; r < 4; ++r) {
                        const int tau = i * 16 + g * 4 + r;
                        EL[tau * 72 + j * 16 + lr] =
                            f2bf((acc[i][j][r] + bn) * (0.125f * 1.44269504f));
                    }
            }
            asm volatile("s_waitcnt lgkmcnt(0)" ::: "memory");
            __builtin_amdgcn_sched_barrier(0);
            #pragma unroll
            for (int it = 0; it < 8; ++it) {
                const int q = it * 64 + l;
                const int tau = q >> 3, c = q & 7;
                *(short8*)(qbf + (rowbase + tau) * 64 + c * 8) =
                    *(const short8*)(EL + tau * 72 + c * 8);
            }
        } else if (which == 1) {
            #pragma unroll
            for (int j = 0; j < 4; ++j) {
                const float bn = bias[nbase + j * 16 + lr];
                #pragma unroll
                for (int i = 0; i < 4; ++i)
                    #pragma unroll
                    for (int r = 0; r < 4; ++r) {
                        const int tau = i * 16 + g * 4 + r;
                        const float v = acc[i][j][r] + bn;
                        EL[tau * 72 + j * 16 + lr] = f2bf(v);
                        outK[(rowbase + tau) * 64 + j * 16 + lr] = v;
                    }
            }
            asm volatile("s_waitcnt lgkmcnt(0)" ::: "memory");
            __builtin_amdgcn_sched_barrier(0);
            #pragma unroll
            for (int it = 0; it < 8; ++it) {
                const int q = it * 64 + l;
                const int tau = q >> 3, c = q & 7;
                *(short8*)(kbf + (rowbase + tau) * 64 + c * 8) =
                    *(const short8*)(EL + tau * 72 + c * 8);
            }
        } else {
            #pragma unroll
            for (int j = 0; j < 4; ++j) {
                const float bn = bias[nbase + j * 16 + lr];
                #pragma unroll
                for (int i = 0; i < 4; ++i)
                    #pragma unroll
                    for (int r = 0; r < 4; ++r) {
                        const int tau = i * 16 + g * 4 + r;
                        const float v = acc[i][j][r] + bn;
                        outV[(rowbase + tau) * 64 + j * 16 + lr] = v;
                        EL[(j * 16 + lr) * 72 + tau] = f2bf(v);   // [dd][tau]
                    }
            }
            asm volatile("s_waitcnt lgkmcnt(0)" ::: "memory");
            __builtin_amdgcn_sched_barrier(0);
            u16* vt = vtb + (size_t)(b * 12 + h) * 65536 + tt0;
            #pragma unroll
            for (int it = 0; it < 8; ++it) {
                const int q = it * 64 + l;
                const int dd = q >> 3, c = q & 7;
                *(short8*)(vt + (size_t)dd * 1024 + c * 8) =
                    *(const short8*)(EL + dd * 72 + c * 8);
            }
        }
    } else {
        #pragma unroll
        for (int j = 0; j < 4; ++j) {
            const int n = n0 + wn + j * 16 + lr;
            const float bn = bias[n];
            #pragma unroll
            for (int i = 0; i < 4; ++i)
                #pragma unroll
                for (int r = 0; r < 4; ++r) {
                    const int m = m0 + wm + i * 16 + g * 4 + r;
                    outP[(size_t)m * 768 + n] = acc[i][j][r] + bn;
                }
        }
    }
#undef ASP
#undef BSP
}

// ---------------- proj GEMM: 128x96 tile -> 512 blocks = exactly 2/CU, balanced ----------------
__global__ __launch_bounds__(256, 3) void gemm_proj_kernel(
    const u16* __restrict__ A, const u16* __restrict__ BT,
    const float* __restrict__ bias, float* __restrict__ outP)
{
    __shared__ alignas(16) u16 As[3][128 * 32];   // 8 KB each
    __shared__ alignas(16) u16 Bs[3][96 * 32];    // 6 KB each  (42 KB total)
    const int t   = threadIdx.x;
    const int wid = t >> 6, l = t & 63;
    const int lr  = l & 15, g = l >> 4;
    const int m0  = blockIdx.x * 128, n0 = blockIdx.y * 96;
    const int wm  = (wid >> 1) * 64, wn = (wid & 1) * 48;

    const int srow = t >> 2;
    const int sch  = ((t & 3) ^ ((srow >> 1) & 3)) * 8;
    const u16* ga0 = A  + (size_t)(m0 + srow) * 768 + sch;
    const u16* ga1 = A  + (size_t)(m0 + 64 + srow) * 768 + sch;
    const u16* gb0 = BT + (size_t)(n0 + srow) * 768 + sch;
    const u16* gb1 = BT + (size_t)(n0 + 64 + srow) * 768 + sch;  // rows 64-95, t<128
    const bool doB1 = (t < 128);

#define GSTAGE(buf, kt) do {                                        \
        gload16(ga0 + (kt) * 32, As[buf] + t * 8);                  \
        gload16(ga1 + (kt) * 32, As[buf] + 2048 + t * 8);           \
        gload16(gb0 + (kt) * 32, Bs[buf] + t * 8);                  \
        if (doB1) gload16(gb1 + (kt) * 32, Bs[buf] + 2048 + t * 8); \
    } while (0)

    const int fco = (g ^ ((lr >> 1) & 3)) * 8;

    f32x4 acc[4][3] = {};

#define COMPUTE(buf) do {                                                 \
        const u16* aB = As[buf];                                          \
        const u16* bB = Bs[buf];                                          \
        short8 af[4], bfr[3];                                             \
        _Pragma("unroll")                                                 \
        for (int i = 0; i < 4; ++i)                                       \
            af[i] = *(const short8*)(aB + (wm + i * 16 + lr) * 32 + fco); \
        _Pragma("unroll")                                                 \
        for (int j = 0; j < 3; ++j)                                       \
            bfr[j] = *(const short8*)(bB + (wn + j * 16 + lr) * 32 + fco);\
        __builtin_amdgcn_s_setprio(1);                                    \
        _Pragma("unroll")                                                 \
        for (int i = 0; i < 4; ++i)                                       \
            _Pragma("unroll")                                             \
            for (int j = 0; j < 3; ++j)                                   \
                acc[i][j] = MFMA16x16x32(af[i], bfr[j], acc[i][j], 0, 0, 0);\
        __builtin_amdgcn_s_setprio(0);                                    \
    } while (0)

#define WAITBAR(N) do {                                           \
        asm volatile("s_waitcnt vmcnt(" #N ")" ::: "memory");     \
        __builtin_amdgcn_s_barrier();                             \
        __builtin_amdgcn_sched_barrier(0);                        \
    } while (0)

    GSTAGE(0, 0); GSTAGE(1, 1);
    WAITBAR(3);

    #pragma unroll 1
    for (int i = 0; i < 7; ++i) {
        const int kt = i * 3;
        GSTAGE(2, kt + 2); COMPUTE(0); WAITBAR(3);
        GSTAGE(0, kt + 3); COMPUTE(1); WAITBAR(3);
        GSTAGE(1, kt + 4); COMPUTE(2); WAITBAR(3);
    }
    GSTAGE(2, 23); COMPUTE(0); WAITBAR(3);
    COMPUTE(1); WAITBAR(0);
    COMPUTE(2);
#undef GSTAGE
#undef COMPUTE
#undef WAITBAR

    #pragma unroll
    for (int j = 0; j < 3; ++j) {
        const int n = n0 + wn + j * 16 + lr;
        const float bn = bias[n];
        #pragma unroll
        for (int i = 0; i < 4; ++i)
            #pragma unroll
            for (int r = 0; r < 4; ++r) {
                const int m = m0 + wm + i * 16 + g * 4 + r;
                outP[(size_t)m * 768 + n] = acc[i][j][r] + bn;
            }
    }
}

// ---------------- causal flash attention, LDS-staged K AND V (round-13 proven) ----------------
__global__ __launch_bounds__(256, 3) void attn_kernel(
    const u16* __restrict__ Qb, const u16* __restrict__ Kb,
    const u16* __restrict__ Vt, u16* __restrict__ Ob)
{
    __shared__ alignas(16) u16 Ks[2][4096];     // [64 kt][8 chunks of 8 u16], swizzled
    __shared__ alignas(16) u16 Vs[2][4096];     // [64 d ][8 chunks of 8 u16], swizzled
    __shared__ alignas(16) u16 Pl[4][16 * 72];  // per-wave P: 16 q x (64+8 pad) u16
    const int bh = blockIdx.x;
    const int t = threadIdx.x;
    const int wid = t >> 6, l = t & 63;
    const int c = l & 15, g = l >> 4;
    u16* P = Pl[wid];
    const u16* Kp = Kb + (size_t)bh * 65536;    // [T][64]
    const u16* Vp = Vt + (size_t)bh * 65536;    // [64][T]
    const int b = bh / 12, h = bh - (bh / 12) * 12;

    const int srow = t >> 3;
    const int sch  = (t & 7) ^ (srow & 7);
    const u16* Ksrc0 = Kp + (size_t)srow * 64 + sch * 8;
    const u16* Ksrc1 = Kp + (size_t)(srow + 32) * 64 + sch * 8;
    const u16* Vsrc0 = Vp + (size_t)srow * 1024 + sch * 8;
    const u16* Vsrc1 = Vp + (size_t)(srow + 32) * 1024 + sch * 8;

    const int fo0 = c * 64 + ((g ^ (c & 7)) * 8);
    const int fo1 = c * 64 + (((g + 4) ^ (c & 7)) * 8);

#define STAGE(buf, kt0) do {                                        \
        gload16(Ksrc0 + (size_t)(kt0) * 64, Ks[buf] + t * 8);       \
        gload16(Ksrc1 + (size_t)(kt0) * 64, Ks[buf] + 2048 + t * 8);\
        gload16(Vsrc0 + (kt0),              Vs[buf] + t * 8);       \
        gload16(Vsrc1 + (kt0),              Vs[buf] + 2048 + t * 8);\
    } while (0)

    #pragma unroll 1
    for (int pass = 0; pass < 2; ++pass) {
        const int tile = pass ? (15 - blockIdx.y) : blockIdx.y;
        const int qbase = tile * 64 + wid * 16;
        const int qg = qbase + c;                // this lane's q column
        const u16* Qp = Qb + ((size_t)bh * 1024 + qg) * 64 + g * 8;
        const short8 bq0 = *(const short8*)(Qp);
        const short8 bq1 = *(const short8*)(Qp + 32);

        f32x4 oacc[4] = {};
        float mrow = -INF, lpart = 0.f;
        const int nb = tile + 1;                 // 64-wide KV blocks

        STAGE(0, 0);
        __syncthreads();
        int cur = 0;

        #pragma unroll 1
        for (int kb = 0; kb < nb; ++kb) {
            if (kb + 1 < nb) STAGE(cur ^ 1, (kb + 1) << 6);
            const u16* kB = Ks[cur];
            const u16* vB = Vs[cur];
            short8 af0[4], af1[4], vf0[4], vf1[4];
            #pragma unroll
            for (int j = 0; j < 4; ++j) {
                af0[j] = *(const short8*)(kB + j * 1024 + fo0);
                af1[j] = *(const short8*)(kB + j * 1024 + fo1);
            }
            #pragma unroll
            for (int dt = 0; dt < 4; ++dt) {
                vf0[dt] = *(const short8*)(vB + dt * 1024 + fo0);
                vf1[dt] = *(const short8*)(vB + dt * 1024 + fo1);
            }
            // QK^T: D[kt][q], s[j] covers kt rows j*16 + g*4 + r
            f32x4 s[4] = {};
            __builtin_amdgcn_s_setprio(1);
            #pragma unroll
            for (int j = 0; j < 4; ++j) {
                s[j] = MFMA16x16x32(af0[j], bq0, s[j], 0, 0, 0);
                s[j] = MFMA16x16x32(af1[j], bq1, s[j], 0, 0, 0);
            }
            __builtin_amdgcn_s_setprio(0);
            if (kb == nb - 1) {                  // only diagonal block masks
                const int kt0 = kb << 6;
                #pragma unroll
                for (int j = 0; j < 4; ++j)
                    #pragma unroll
                    for (int r = 0; r < 4; ++r)
                        if (kt0 + j * 16 + g * 4 + r > qg) s[j][r] = -INF;
            }
            // softmax (scores already in log2 units); tree max
            f32x4 mm = max4(max4(s[0], s[1]), max4(s[2], s[3]));
            float tm = fmaxf(fmaxf(mm.x, mm.y), fmaxf(mm.z, mm.w));
            tm = fmaxf(tm, __shfl_xor(tm, 16));
            tm = fmaxf(tm, __shfl_xor(tm, 32));
            // defer-max (T13): skip rescale while growth <= 8 (log2 units)
            const bool keep = (__all(tm <= mrow + 8.f) != 0);
            const float mnew = keep ? mrow : fmaxf(mrow, tm);
            if (!keep) {
                const float sc = exp2f(mrow - mnew);
                mrow = mnew;
                lpart *= sc;
                #pragma unroll
                for (int dt = 0; dt < 4; ++dt) {
                    oacc[dt][0] *= sc; oacc[dt][1] *= sc;
                    oacc[dt][2] *= sc; oacc[dt][3] *= sc;
                }
            }
            f32x4 p[4];
            #pragma unroll
            for (int j = 0; j < 4; ++j) {
                p[j].x = exp2f(s[j].x - mnew); p[j].y = exp2f(s[j].y - mnew);
                p[j].z = exp2f(s[j].z - mnew); p[j].w = exp2f(s[j].w - mnew);
            }
            f32x4 ps = add4(add4(p[0], p[1]), add4(p[2], p[3]));
            lpart += (ps.x + ps.y) + (ps.z + ps.w);
            // P[q=c][kt] bf16 -> LDS (row stride 72 u16, 2-way conflicts only)
            #pragma unroll
            for (int j = 0; j < 4; ++j) {
                short4v w;
                w.x = (short)f2bf(p[j].x); w.y = (short)f2bf(p[j].y);
                w.z = (short)f2bf(p[j].z); w.w = (short)f2bf(p[j].w);
                *(short4v*)(P + c * 72 + j * 16 + g * 4) = w;
            }
            const short8 pf0 = *(const short8*)(P + c * 72 + g * 8);
            const short8 pf1 = *(const short8*)(P + c * 72 + 32 + g * 8);
            // PV: A = V^T rows (d), B = P^T -> D[d][q]
            __builtin_amdgcn_s_setprio(1);
            #pragma unroll
            for (int dt = 0; dt < 4; ++dt) {
                oacc[dt] = MFMA16x16x32(vf0[dt], pf0, oacc[dt], 0, 0, 0);
                oacc[dt] = MFMA16x16x32(vf1[dt], pf1, oacc[dt], 0, 0, 0);
            }
            __builtin_amdgcn_s_setprio(0);
            __syncthreads();   // drains staging (vmcnt 0) + all waves done with buf cur
            cur ^= 1;
        }
        float lsum = lpart;
        lsum += __shfl_xor(lsum, 16);
        lsum += __shfl_xor(lsum, 32);
        const float li = 1.f / lsum;             // lane-local (col=q layout)
        // O-write via per-wave LDS reorder -> 2x16-B coalesced stores/lane
        #pragma unroll
        for (int dt = 0; dt < 4; ++dt) {
            short4v w;
            w.x = (short)f2bf(oacc[dt][0] * li);
            w.y = (short)f2bf(oacc[dt][1] * li);
            w.z = (short)f2bf(oacc[dt][2] * li);
            w.w = (short)f2bf(oacc[dt][3] * li);
            *(short4v*)(P + c * 72 + dt * 16 + g * 4) = w;
        }
        asm volatile("s_waitcnt lgkmcnt(0)" ::: "memory");
        __builtin_amdgcn_sched_barrier(0);
        #pragma unroll
        for (int it = 0; it < 2; ++it) {
            const int idx = it * 64 + l;
            const int q = idx >> 3, ch = idx & 7;
            *(short8*)(Ob + (size_t)(b * 1024 + qbase + q) * 768 + h * 64 + ch * 8) =
                *(const short8*)(P + q * 72 + ch * 8);
        }
    }
#undef STAGE
}

extern "C" void kernel_launch(void* const* d_in, const int* in_sizes, int n_in,
                              void* d_out, int out_size, void* d_ws, size_t ws_size,
                              hipStream_t stream) {
    const float* hs = (const float*)d_in[0];   // [8,1024,768]
    const float* Wa = (const float*)d_in[1];   // [768,2304]
    const float* ba = (const float*)d_in[2];   // [2304]
    const float* Wp = (const float*)d_in[3];   // [768,768]
    const float* bp = (const float*)d_in[4];   // [768]
    float* out = (float*)d_out;                // out | K | V  (each NOUT fp32)

    u16* ws  = (u16*)d_ws;
    u16* Xbf = ws;                             // [8192][768]
    u16* WaT = Xbf + NOUT;                     // [2304][768]
    u16* WpT = WaT + 768 * 2304;               // [768][768]
    u16* Qbf = WpT + 768 * 768;                // [B,H,T,64] (pre-scaled by 0.125*log2e)
    u16* Kbf = Qbf + NOUT;                     // [B,H,T,64]
    u16* VTb = Kbf + NOUT;                     // [B,H,64,T]
    u16* Obf = VTb + NOUT;                     // [8192][768]

    prep_kernel<<<8448, 256, 0, stream>>>(hs, Xbf, Wa, WaT, Wp, WpT);
    gemm_k768_kernel<0><<<dim3(64, 18), 256, 0, stream>>>(
        Xbf, WaT, ba, Qbf, Kbf, VTb, out + NOUT, out + 2 * (size_t)NOUT, nullptr);
    attn_kernel<<<dim3(96, 8), 256, 0, stream>>>(Qbf, Kbf, VTb, Obf);
    gemm_proj_kernel<<<dim3(64, 8), 256, 0, stream>>>(Obf, WpT, bp, out);
}